// Round 12
// baseline (107.330 us; speedup 1.0000x reference)
//
#include <hip/hip_runtime.h>
#include <math.h>
#include <float.h>

// Problem constants (match reference)
#define BATCH 4
#define KCLS 16
#define NSRC 4096
#define NTGT 16384

// geometry (R9, proven): 512 threads = 8 waves; 8 targets/lane; 512 tgt/block;
// 8-way source split across blocks (grid = 1024 -> 4 blocks/CU); 8 KB stage.
#define THREADS 512
#define WAVES 8
#define TPL 8                               // targets per lane (4 float2 groups)
#define GROUPS (TPL / 2)
#define TGT_PER_BLOCK 512
#define SPLITS 8
#define CHUNK (NSRC / SPLITS)               // 512
#define STRIPE (CHUNK / WAVES)              // 64

typedef float v2f __attribute__((ext_vector_type(2)));

// Main kernel: per-(target, source-chunk) argmin partials, bit-exact np
// numerics (verified absmax=0.0 R5-R11):
//   ss/tt: squares rounded individually, then sequential sum
//   dot  : rn(tx*sx); fma(ty,sy,.); fma(tz,sz,.)
//   d2   : fma(-2, dot, rn(tt+ss))
// Inner loop packs 2 targets per v2f: v_pk_mul/v_pk_fma/v_pk_add are IEEE-rn
// per 32-bit half == identical results, half the issue slots for the arith.
// Combine: packed u64 atomicMin of (ordered_float(d2)<<32 | idx)
// == lexicographic (d2, first index) == np.argmin tie-break.
__global__ __launch_bounds__(THREADS) void nn_partial_kernel(
    const float* __restrict__ source_pos,   // [B, 3, NS]
    const float* __restrict__ target_pos,   // [B, 3, NT]
    unsigned long long* __restrict__ ws64)  // [B*NT] packed (ord<<32)|idx
{
    // 32 KB: [0,8K) source stage; aliased after the scan as
    // smin[8][512] (16 KB) | sidx[8][512] (16 KB)
    __shared__ float4 ls[TGT_PER_BLOCK * WAVES / 2];

    int tid = threadIdx.x;
    int lane = tid & 63;
    int wave = tid >> 6;                    // 0..7

    // grid decode: blocksPerBatch = 32 tgroups * 8 splits = 256
    int b = blockIdx.x >> 8;
    int rem = blockIdx.x & 255;
    int tg = rem >> 3;
    int split = rem & 7;
    int tbase = tg * TGT_PER_BLOCK;
    int cg = split * CHUNK;                 // this block's source-chunk base

    // stage chunk: 512 sources, 1 per thread (coalesced x/y/z streams)
    const float* sxp = source_pos + (size_t)b * 3 * NSRC;
    const float* syp = sxp + NSRC;
    const float* szp = sxp + 2 * NSRC;
    {
        int s = tid;                        // CHUNK == THREADS
        float x = sxp[cg + s], y = syp[cg + s], z = szp[cg + s];
        float ss = __fadd_rn(__fadd_rn(__fmul_rn(x, x), __fmul_rn(y, y)),
                             __fmul_rn(z, z));
        ls[s] = make_float4(x, y, z, ss);
    }

    // 8 targets/lane as 4 float2 groups: group g = targets (2g, 2g+1),
    // t_j = tbase + 64*j + lane (coalesced loads)
    const float* tp = target_pos + (size_t)b * 3 * NTGT;
    v2f tx2[GROUPS], ty2[GROUPS], tz2[GROUPS], tt2[GROUPS];
#pragma unroll
    for (int g = 0; g < GROUPS; ++g) {
        int ta = tbase + 64 * (2 * g) + lane;
        int tb_ = tbase + 64 * (2 * g + 1) + lane;
        float xa = tp[ta], ya = tp[NTGT + ta], za = tp[2 * NTGT + ta];
        float xb = tp[tb_], yb = tp[NTGT + tb_], zb = tp[2 * NTGT + tb_];
        float tta = __fadd_rn(__fadd_rn(__fmul_rn(xa, xa), __fmul_rn(ya, ya)),
                              __fmul_rn(za, za));
        float ttb = __fadd_rn(__fadd_rn(__fmul_rn(xb, xb), __fmul_rn(yb, yb)),
                              __fmul_rn(zb, zb));
        tx2[g] = (v2f){xa, xb}; ty2[g] = (v2f){ya, yb};
        tz2[g] = (v2f){za, zb}; tt2[g] = (v2f){tta, ttb};
    }

    __syncthreads();

    int lbase = wave * STRIPE;              // this wave's stripe in the chunk
    int gbase = cg + lbase;                 // global source index base (uniform)
    float best[TPL];
    int bi[TPL];
#pragma unroll
    for (int j = 0; j < TPL; ++j) { best[j] = FLT_MAX; bi[j] = 0; }

    const v2f m2 = (v2f){-2.0f, -2.0f};

#pragma unroll 8
    for (int i = 0; i < STRIPE; ++i) {
        float4 f = ls[lbase + i];           // wave-uniform -> LDS broadcast
        int cand = gbase + i;
        v2f fx = (v2f){f.x, f.x}, fy = (v2f){f.y, f.y};
        v2f fz = (v2f){f.z, f.z}, fw = (v2f){f.w, f.w};
#pragma unroll
        for (int g = 0; g < GROUPS; ++g) {
            v2f acc = tx2[g] * fx;                            // v_pk_mul_f32
            acc = __builtin_elementwise_fma(ty2[g], fy, acc); // v_pk_fma_f32
            acc = __builtin_elementwise_fma(tz2[g], fz, acc); // v_pk_fma_f32
            v2f w = tt2[g] + fw;                              // v_pk_add_f32
            v2f d2 = __builtin_elementwise_fma(m2, acc, w);   // v_pk_fma_f32
            // strict '<' keeps the FIRST minimum (np.argmin tie-break)
            if (d2.x < best[2 * g])     { best[2 * g] = d2.x;     bi[2 * g] = cand; }
            if (d2.y < best[2 * g + 1]) { best[2 * g + 1] = d2.y; bi[2 * g + 1] = cand; }
        }
    }

    __syncthreads();                        // done READING ls before aliasing

    float* smin = (float*)ls;
    int* sidx = (int*)(smin + WAVES * TGT_PER_BLOCK);
#pragma unroll
    for (int j = 0; j < TPL; ++j) {
        smin[wave * TGT_PER_BLOCK + 64 * j + lane] = best[j];
        sidx[wave * TGT_PER_BLOCK + 64 * j + lane] = bi[j];
    }
    __syncthreads();

    {
        int t = tid;                        // TGT_PER_BLOCK == THREADS
        float m = smin[t];
        int mi = sidx[t];
#pragma unroll
        for (int j = 1; j < WAVES; ++j) {
            float mj = smin[j * TGT_PER_BLOCK + t];
            int ij = sidx[j * TGT_PER_BLOCK + t];
            // lexicographic (value, index): earliest global index wins on ties
            if (mj < m || (mj == m && ij < mi)) { m = mj; mi = ij; }
        }
        // total-order map: monotone wrt float '<' (handles negatives)
        unsigned u = __float_as_uint(m);
        unsigned ord = (u & 0x80000000u) ? ~u : (u | 0x80000000u);
        unsigned long long packed =
            ((unsigned long long)ord << 32) | (unsigned)mi;
        atomicMin(&ws64[(size_t)b * NTGT + tbase + t], packed);
    }
}

// Combine: extract winning index from packed u64, lazy gate gather + sigmoid.
__global__ __launch_bounds__(256) void gate_kernel(
    const unsigned long long* __restrict__ ws64,  // [B*NT]
    const float* __restrict__ sem_logits,         // [B, K, NS]
    float* __restrict__ out)                      // [B*NT]
{
    int gt = blockIdx.x * 256 + threadIdx.x;      // 0 .. B*NT-1
    int b = gt / NTGT;
    int mi = (int)(ws64[gt] & 0xFFFFFFFFull);

    const float* lg = sem_logits + (size_t)b * KCLS * NSRC + mi;
    float mm = lg[0];
#pragma unroll
    for (int k = 1; k < KCLS; ++k) mm = fmaxf(mm, lg[(size_t)k * NSRC]);
    out[gt] = 1.0f / (1.0f + expf(-mm));
}

extern "C" void kernel_launch(void* const* d_in, const int* in_sizes, int n_in,
                              void* d_out, int out_size, void* d_ws, size_t ws_size,
                              hipStream_t stream) {
    const float* sem_logits = (const float*)d_in[0];   // [B,K,NS] fp32
    const float* source_pos = (const float*)d_in[1];   // [B,3,NS] fp32
    const float* target_pos = (const float*)d_in[2];   // [B,3,NT] fp32
    float* out = (float*)d_out;                        // [B,NT,1] fp32

    unsigned long long* ws64 = (unsigned long long*)d_ws;  // 512 KB partials

    // init packed partials to u64-max (0xFF bytes)
    hipMemsetAsync(ws64, 0xFF, sizeof(unsigned long long) * BATCH * NTGT, stream);

    nn_partial_kernel<<<BATCH * (NTGT / TGT_PER_BLOCK) * SPLITS, THREADS, 0, stream>>>(
        source_pos, target_pos, ws64);
    gate_kernel<<<(BATCH * NTGT) / 256, 256, 0, stream>>>(ws64, sem_logits, out);
}